// Round 2
// baseline (192.863 us; speedup 1.0000x reference)
//
#include <hip/hip_runtime.h>
#include <cstdint>

// ---------------------------------------------------------------------------
// QuantumCoherentLayer collapsed:
//   out[b,h] = sum_j w[j]*( alpha*coh[b,j,h] + (1-alpha)*(x@Win@Wp[j])[b,h] )
//   w[j] = (alpha/64) * colsum_j( softmax_rows( cos(phase * J_sym) ) )
// Pipeline: k_prep (convert x/Win to bf16 + build Weff^T) ->
//           k_gemm<64,0>  Wc^T = Weff^T @ Win^T-free   (bf16) ->
//           k_gemm<128,1> out = x@Wc + coh-reduction (coh streamed in-loop)
// ---------------------------------------------------------------------------

typedef __attribute__((ext_vector_type(8))) __bf16 bf16x8;
typedef __attribute__((ext_vector_type(4))) float f32x4;

__device__ __forceinline__ unsigned short f32_to_bf16_rne(float f) {
  unsigned int u = __float_as_uint(f);
  u += 0x7fffu + ((u >> 16) & 1u);
  return (unsigned short)(u >> 16);
}

__device__ __forceinline__ void load16_lds(const void* g, void* l) {
  __builtin_amdgcn_global_load_lds(
      (const __attribute__((address_space(1))) void*)g,
      (__attribute__((address_space(3))) void*)(unsigned int)(unsigned long long)l,
      16, 0, 0);
}

// Executed by 64 lanes of one wave. out_lo[j] = w_j*(1-a), out_hi[j] = w_j*a.
__device__ __forceinline__ void compute_scalars_wave(
    const float* __restrict__ J, const float* __restrict__ t,
    float* out_lo, float* out_hi) {
  const int lane = threadIdx.x & 63;
  float tv = t[0];
  float alpha = fminf(fmaxf(expf(-tv / 51.0f), 0.0f), 1.0f);
  float phase = 2.0f * 3.14159265358979323846f * 20.0f * tv / 1000.0f;
  int i = lane >> 3, j = lane & 7;
  float jsym = 0.5f * (J[i * 8 + j] + J[j * 8 + i]);
  float e = expf(cosf(phase * jsym));
  float rs = e;
  rs += __shfl_xor(rs, 1);
  rs += __shfl_xor(rs, 2);
  rs += __shfl_xor(rs, 4);
  float p = e / rs;
  float cs = p;
  cs += __shfl_xor(cs, 8);
  cs += __shfl_xor(cs, 16);
  cs += __shfl_xor(cs, 32);
  float w = alpha * (1.0f / 64.0f) * cs;
  if (lane < 8) {
    if (out_lo) out_lo[lane] = w * (1.0f - alpha);
    if (out_hi) out_hi[lane] = w * alpha;
  }
}

// ---------------------------------------------------------------------------
// k_prep: blocks [0,3072) convert x,Win fp32->bf16 (float4/thread);
//         blocks [3072,4096) build Weff^T tiles (32x32 transpose via LDS).
// ---------------------------------------------------------------------------
__global__ __launch_bounds__(256) void k_prep(
    const float* __restrict__ x, const float* __restrict__ win,
    const float* __restrict__ wp, const float* __restrict__ J,
    const float* __restrict__ t, unsigned short* __restrict__ xb,
    unsigned short* __restrict__ winb, unsigned short* __restrict__ wefft) {
  __shared__ float sw[8];
  __shared__ float lt[32][33];
  const int blk = blockIdx.x;
  const int tid = threadIdx.x;
  if (blk < 3072) {
    int idx = blk * 256 + tid;
    const float4* src;
    unsigned short* dst;
    int off;
    if (idx < 524288) { src = (const float4*)x;   dst = xb;   off = idx; }
    else              { src = (const float4*)win; dst = winb; off = idx - 524288; }
    float4 v = src[off];
    ushort4 o;
    o.x = f32_to_bf16_rne(v.x);
    o.y = f32_to_bf16_rne(v.y);
    o.z = f32_to_bf16_rne(v.z);
    o.w = f32_to_bf16_rne(v.w);
    ((ushort4*)dst)[off] = o;
  } else {
    if (tid < 64) compute_scalars_wave(J, t, sw, nullptr);
    __syncthreads();
    const int q = blk - 3072;
    const int tx = tid & 31, ty = tid >> 5;
    const int k0 = (q & 31) * 32, h0 = (q >> 5) * 32;
    float acc[4] = {0.f, 0.f, 0.f, 0.f};
#pragma unroll
    for (int j = 0; j < 8; j++) {
      const float* base = wp + (size_t)j * 1024 * 1024;
      float wj = sw[j];
#pragma unroll
      for (int r = 0; r < 4; r++)
        acc[r] += wj * base[(size_t)(h0 + ty + 8 * r) * 1024 + k0 + tx];
    }
#pragma unroll
    for (int r = 0; r < 4; r++) lt[ty + 8 * r][tx] = acc[r];
    __syncthreads();
#pragma unroll
    for (int r = 0; r < 4; r++)
      wefft[(size_t)(k0 + ty + 8 * r) * 1024 + h0 + tx] =
          f32_to_bf16_rne(lt[tx][ty + 8 * r]);
  }
}

// ---------------------------------------------------------------------------
// GEMM: C[m][n] = sum_k A[m][k]*B[n][k], bf16 row-major (K=1024, BK=64, BN=64).
// BM in {64,128}. 4 waves in 2x2; wave tile (BM/2)x32 via 16x16x32 MFMA.
// global_load_lds width-16 staging, XOR-swizzled 16B k-groups (8 groups/row).
// MAIN=1: streams coh [M][8][1024] inside the K-loop (weighted p-reduction
//   into registers -> LDS), epilogue writes fp32 acc + cohacc.
// MAIN=0: writes bf16.
// ---------------------------------------------------------------------------
template <int BM, int MAIN>
__global__ __launch_bounds__(256) void k_gemm(
    const unsigned short* __restrict__ A, const unsigned short* __restrict__ B,
    float* __restrict__ outf, unsigned short* __restrict__ outb,
    const float* __restrict__ coh, const float* __restrict__ J,
    const float* __restrict__ t) {
  constexpr int K = 1024;
  constexpr int BN = 64;
  constexpr int BK = 64;
  constexpr int FM = BM / 32;  // m-frags per wave
  constexpr int NA = BM / 32;  // A staging insts per wave (1KB each)
  __shared__ alignas(16) unsigned short As[BM * BK];
  __shared__ alignas(16) unsigned short Bs[BN * BK];
  __shared__ float sm_s[8];
  __shared__ float cohacc[MAIN ? BM * BN : 4];

  const int m0 = blockIdx.x * BM;
  const int n0 = blockIdx.y * BN;
  const int tid = threadIdx.x;
  const int wave = tid >> 6;
  const int lane = tid & 63;
  const int quad = lane >> 4;
  const int t16 = lane & 15;

  float wA[8];
  if constexpr (MAIN) {
    if (tid < 64) compute_scalars_wave(J, t, nullptr, sm_s);
    __syncthreads();
#pragma unroll
    for (int p = 0; p < 8; p++) wA[p] = sm_s[p];
  }

  // staging addresses: 1KB chunk = 8 rows x 8 groups of 16B, swizzled
  const int srow = lane >> 3;  // row within chunk
  const int sgrp = lane & 7;   // LDS 16B group
  const unsigned short* gA[NA];
  unsigned short* lA[NA];
#pragma unroll
  for (int c = 0; c < NA; c++) {
    int r = (wave * NA + c) * 8 + srow;
    int gcol = sgrp ^ (r & 7);
    gA[c] = A + (size_t)(m0 + r) * K + gcol * 8;
    lA[c] = As + (wave * NA + c) * 512 + lane * 8;
  }
  const unsigned short* gB[2];
  unsigned short* lB[2];
#pragma unroll
  for (int c = 0; c < 2; c++) {
    int r = (wave * 2 + c) * 8 + srow;
    int gcol = sgrp ^ (r & 7);
    gB[c] = B + (size_t)(n0 + r) * K + gcol * 8;
    lB[c] = Bs + (wave * 2 + c) * 512 + lane * 8;
  }

  const int wm = (wave >> 1) * (BM / 2);
  const int wn = (wave & 1) * 32;
  const unsigned short* pa[FM][2];
  const unsigned short* pb[2][2];
#pragma unroll
  for (int mi = 0; mi < FM; mi++) {
    int r = wm + mi * 16 + t16;
#pragma unroll
    for (int kk = 0; kk < 2; kk++)
      pa[mi][kk] = As + r * BK + (((kk * 4 + quad) ^ (r & 7)) * 8);
  }
#pragma unroll
  for (int ni = 0; ni < 2; ni++) {
    int r = wn + ni * 16 + t16;
#pragma unroll
    for (int kk = 0; kk < 2; kk++)
      pb[ni][kk] = Bs + r * BK + (((kk * 4 + quad) ^ (r & 7)) * 8);
  }

  f32x4 acc[FM][2];
#pragma unroll
  for (int mi = 0; mi < FM; mi++)
#pragma unroll
    for (int ni = 0; ni < 2; ni++) acc[mi][ni] = {0.f, 0.f, 0.f, 0.f};

  f32x4 cacc[8];
  const float* cbase = nullptr;
  if constexpr (MAIN) {
#pragma unroll
    for (int s = 0; s < 8; s++) cacc[s] = {0.f, 0.f, 0.f, 0.f};
    cbase = coh + (size_t)(m0 + (tid >> 4)) * 8192 + n0 + (tid & 15) * 4;
  }

  for (int it = 0; it < K / BK; it++) {
    const int kt = it * BK;
    __syncthreads();
#pragma unroll
    for (int c = 0; c < NA; c++) load16_lds(gA[c] + kt, lA[c]);
#pragma unroll
    for (int c = 0; c < 2; c++) load16_lds(gB[c] + kt, lB[c]);
    if constexpr (MAIN) {
      // stream this block's coh slice: iter it covers slot s=it/2, 4 p's
      const int s = it >> 1, p0 = (it & 1) * 4;
      const float* cp = cbase + (size_t)(s << 4) * 8192;
#pragma unroll
      for (int pp = 0; pp < 4; pp++) {
        f32x4 v = *(const f32x4*)(cp + (p0 + pp) * 1024);
        cacc[s] += wA[p0 + pp] * v;
      }
    }
    __syncthreads();
#pragma unroll
    for (int kk = 0; kk < 2; kk++) {
      bf16x8 a[FM], b[2];
#pragma unroll
      for (int mi = 0; mi < FM; mi++) a[mi] = *(const bf16x8*)pa[mi][kk];
#pragma unroll
      for (int ni = 0; ni < 2; ni++) b[ni] = *(const bf16x8*)pb[ni][kk];
#pragma unroll
      for (int mi = 0; mi < FM; mi++)
#pragma unroll
        for (int ni = 0; ni < 2; ni++)
          acc[mi][ni] = __builtin_amdgcn_mfma_f32_16x16x32_bf16(
              a[mi], b[ni], acc[mi][ni], 0, 0, 0);
    }
  }

  if constexpr (MAIN) {
    const int m_l = tid >> 4, nq = (tid & 15) * 4;
#pragma unroll
    for (int s = 0; s < 8; s++)
      *(f32x4*)&cohacc[(m_l + (s << 4)) * BN + nq] = cacc[s];
    __syncthreads();
  }

  // epilogue: C row = quad*4 + reg, col = t16 (m89-verified layout)
#pragma unroll
  for (int mi = 0; mi < FM; mi++) {
#pragma unroll
    for (int r = 0; r < 4; r++) {
      const int ml = wm + mi * 16 + quad * 4 + r;
      const int m = m0 + ml;
#pragma unroll
      for (int ni = 0; ni < 2; ni++) {
        const int nl = wn + ni * 16 + t16;
        if constexpr (MAIN) {
          outf[(size_t)m * 1024 + n0 + nl] = acc[mi][ni][r] + cohacc[ml * BN + nl];
        } else {
          outb[(size_t)m * 1024 + n0 + nl] = f32_to_bf16_rne(acc[mi][ni][r]);
        }
      }
    }
  }
}

// ---------------------------------------------------------------------------
extern "C" void kernel_launch(void* const* d_in, const int* in_sizes, int n_in,
                              void* d_out, int out_size, void* d_ws, size_t ws_size,
                              hipStream_t stream) {
  const float* x   = (const float*)d_in[0];  // [2048,1024]
  const float* win = (const float*)d_in[1];  // [1024,1024]
  const float* wp  = (const float*)d_in[2];  // [8,1024,1024]
  const float* J   = (const float*)d_in[3];  // [8,8]
  const float* coh = (const float*)d_in[4];  // [2048,8,1024]
  const float* t   = (const float*)d_in[5];  // [1]
  float* out = (float*)d_out;                // [2048,1024] fp32

  char* ws = (char*)d_ws;
  unsigned short* xb    = (unsigned short*)ws;                              // 4 MB
  unsigned short* winb  = (unsigned short*)(ws + 4u * 1024 * 1024);         // 2 MB
  unsigned short* wefft = (unsigned short*)(ws + 6u * 1024 * 1024);         // 2 MB
  unsigned short* wct   = (unsigned short*)(ws + 8u * 1024 * 1024);         // 2 MB

  // convert + Weff^T build (scalars computed inline)
  k_prep<<<4096, 256, 0, stream>>>(x, win, wp, J, t, xb, winb, wefft);
  // Wct[h][d] = sum_h1 Weff_t[h][h1] * Win[d][h1]
  k_gemm<64, 0><<<dim3(16, 16), 256, 0, stream>>>(wefft, winb, nullptr, wct,
                                                  nullptr, nullptr, nullptr);
  // out[b][h] = sum_d x[b][d]*Wct[h][d] + sum_p wA[p]*coh[b][p][h]
  k_gemm<128, 1><<<dim3(16, 16), 256, 0, stream>>>(xb, wct, out, nullptr, coh,
                                                   J, t);
}

// Round 3
// 162.288 us; speedup vs baseline: 1.1884x; 1.1884x over previous
//
#include <hip/hip_runtime.h>
#include <cstdint>

// ---------------------------------------------------------------------------
// QuantumCoherentLayer collapsed:
//   out[b,h] = sum_p wHI[p]*coh[b,p,h] + (x @ Win @ WeffLO)[b,h]
//   w[j]   = (alpha/64) * colsum_j( softmax_rows( cos(phase*J_sym) ) )
//   wLO[j] = w[j]*(1-alpha) (folded into Weff), wHI[j] = w[j]*alpha
// Pipeline (3 kernels):
//   k_prep : x->bf16, Win->bf16, coh partial -> out (fp32), Weff^T (bf16)
//   k_gemm<0>: wct[h2][d] = sum_h1 wefft[h2][h1] * winb[d][h1]   (bf16)
//   k_gemm<1>: out[b][h2] += sum_d xb[b][d] * wct[h2][d]         (RMW fp32)
// Design: small tiles (BM=64,BN=32,BK=64), 1024/512 blocks -> 4/2 blocks/CU
// so barrier drains interleave across blocks (latency-hiding via occupancy).
// ---------------------------------------------------------------------------

typedef __attribute__((ext_vector_type(8))) __bf16 bf16x8;
typedef __attribute__((ext_vector_type(4))) float f32x4;

__device__ __forceinline__ unsigned short f32_to_bf16_rne(float f) {
  unsigned int u = __float_as_uint(f);
  u += 0x7fffu + ((u >> 16) & 1u);
  return (unsigned short)(u >> 16);
}

__device__ __forceinline__ void load16_lds(const void* g, void* l) {
  __builtin_amdgcn_global_load_lds(
      (const __attribute__((address_space(1))) void*)g,
      (__attribute__((address_space(3))) void*)(unsigned int)(unsigned long long)l,
      16, 0, 0);
}

// Per-wave scalar computation; every lane ends with w for j=(lane&7), and
// alpha. Lanes gather all 8 via shuffles (no LDS, no barrier).
__device__ __forceinline__ void wave_scalars(const float* __restrict__ J,
                                             const float* __restrict__ t,
                                             float* w_out, float* alpha_out) {
  const int lane = threadIdx.x & 63;
  float tv = t[0];
  float alpha = fminf(fmaxf(expf(-tv / 51.0f), 0.0f), 1.0f);
  float phase = 2.0f * 3.14159265358979323846f * 20.0f * tv / 1000.0f;
  int i = lane >> 3, j = lane & 7;
  float jsym = 0.5f * (J[i * 8 + j] + J[j * 8 + i]);
  float e = expf(cosf(phase * jsym));
  float rs = e;                      // softmax denom over j (within 8-lane row)
  rs += __shfl_xor(rs, 1);
  rs += __shfl_xor(rs, 2);
  rs += __shfl_xor(rs, 4);
  float p = e / rs;
  float cs = p;                      // column sum over i (stride 8)
  cs += __shfl_xor(cs, 8);
  cs += __shfl_xor(cs, 16);
  cs += __shfl_xor(cs, 32);
  *w_out = alpha * (1.0f / 64.0f) * cs;  // valid for j = lane&7
  *alpha_out = alpha;
}

// ---------------------------------------------------------------------------
// k_prep, grid-partitioned streaming (5376 blocks x 256):
//  [0,2048)    : x fp32->bf16, float4/thread
//  [2048,3072) : Win fp32->bf16
//  [3072,5120) : out[b][h] = sum_p wHI[p]*coh[b][p][h]  (fp32 partial)
//  [5120,5376) : wefft[h2][h1] = sum_j wLO[j]*Wp[j][h1][h2] (64x64 LDS transp)
// ---------------------------------------------------------------------------
__global__ __launch_bounds__(256, 4) void k_prep(
    const float* __restrict__ x, const float* __restrict__ win,
    const float* __restrict__ wp, const float* __restrict__ J,
    const float* __restrict__ t, const float* __restrict__ coh,
    unsigned short* __restrict__ xb, unsigned short* __restrict__ winb,
    unsigned short* __restrict__ wefft, float* __restrict__ out) {
  const int blk = blockIdx.x;
  const int tid = threadIdx.x;
  const int lane = tid & 63;

  if (blk < 3072) {  // converts
    int idx = blk * 256 + tid;
    const float4* src;
    unsigned short* dst;
    int off;
    if (idx < 524288) { src = (const float4*)x;   dst = xb;   off = idx; }
    else              { src = (const float4*)win; dst = winb; off = idx - 524288; }
    float4 v = src[off];
    ushort4 o;
    o.x = f32_to_bf16_rne(v.x);
    o.y = f32_to_bf16_rne(v.y);
    o.z = f32_to_bf16_rne(v.z);
    o.w = f32_to_bf16_rne(v.w);
    ((ushort4*)dst)[off] = o;
  } else if (blk < 5120) {  // coh partial -> out
    float wv, alpha;
    wave_scalars(J, t, &wv, &alpha);
    float wHI[8];
#pragma unroll
    for (int p = 0; p < 8; p++) wHI[p] = __shfl(wv, (lane & 56) | p) * alpha;
    int idx = (blk - 3072) * 256 + tid;      // [0, 524288) float4 of out
    int b = idx >> 8, hq = idx & 255;
    const f32x4* cb = (const f32x4*)(coh + (size_t)b * 8192) + hq;
    f32x4 acc = {0.f, 0.f, 0.f, 0.f};
#pragma unroll
    for (int p = 0; p < 8; p++) acc += wHI[p] * cb[p * 256];
    ((f32x4*)out)[idx] = acc;
  } else {  // wefft build
    __shared__ float lt[64][69];
    float wv, alpha;
    wave_scalars(J, t, &wv, &alpha);
    float wLO[8];
#pragma unroll
    for (int p = 0; p < 8; p++)
      wLO[p] = __shfl(wv, (lane & 56) | p) * (1.0f - alpha);
    const int q = blk - 5120;                 // 256 blocks: 16x16 of 64x64
    const int a0 = (q & 15) * 64;             // h1 tile (rows of Wp)
    const int b0 = (q >> 4) * 64;             // h2 tile (cols of Wp)
    const int rb = tid >> 4, c = tid & 15;    // read: 16 rows/pass x 16 float4
    f32x4 acc[4];
#pragma unroll
    for (int s = 0; s < 4; s++) acc[s] = {0.f, 0.f, 0.f, 0.f};
#pragma unroll
    for (int j = 0; j < 8; j++) {
      const float* base = wp + (size_t)j * 1024 * 1024 + b0 + c * 4;
      float wj = wLO[j];
#pragma unroll
      for (int s = 0; s < 4; s++) {
        f32x4 v = *(const f32x4*)(base + (size_t)(a0 + rb + 16 * s) * 1024);
        acc[s] += wj * v;
      }
    }
#pragma unroll
    for (int s = 0; s < 4; s++)
#pragma unroll
      for (int e = 0; e < 4; e++) lt[rb + 16 * s][c * 4 + e] = acc[s][e];
    __syncthreads();
    // write transposed: thread -> 16 bf16 (32B) of row h2l
    const int h2l = tid >> 2, h1g = (tid & 3) * 16;
    unsigned short* dst = wefft + (size_t)(b0 + h2l) * 1024 + a0 + h1g;
#pragma unroll
    for (int v4 = 0; v4 < 4; v4++) {
      ushort4 o;
      o.x = f32_to_bf16_rne(lt[h1g + v4 * 4 + 0][h2l]);
      o.y = f32_to_bf16_rne(lt[h1g + v4 * 4 + 1][h2l]);
      o.z = f32_to_bf16_rne(lt[h1g + v4 * 4 + 2][h2l]);
      o.w = f32_to_bf16_rne(lt[h1g + v4 * 4 + 3][h2l]);
      ((ushort4*)dst)[v4] = o;
    }
  }
}

// ---------------------------------------------------------------------------
// GEMM: C[m][n] = sum_k A[m][k]*B[n][k], bf16, K=1024, BM=64/BN=32/BK=64.
// 4 waves; wave owns 16 m-rows x all 32 n. global_load_lds 16B staging with
// per-row XOR swizzle of 16B k-groups. MAIN=1: fp32 RMW into out.
// ---------------------------------------------------------------------------
template <int MAIN>
__global__ __launch_bounds__(256, 4) void k_gemm(
    const unsigned short* __restrict__ A, const unsigned short* __restrict__ B,
    float* __restrict__ outf, unsigned short* __restrict__ outb) {
  constexpr int K = 1024;
  constexpr int BK = 64;
  __shared__ alignas(16) unsigned short As[64 * BK];  // 8 KB
  __shared__ alignas(16) unsigned short Bs[32 * BK];  // 4 KB

  const int m0 = blockIdx.x * 64;
  const int n0 = blockIdx.y * 32;
  const int tid = threadIdx.x;
  const int wave = tid >> 6;
  const int lane = tid & 63;
  const int quad = lane >> 4;
  const int t16 = lane & 15;

  // --- staging addresses (1KB chunk = 8 rows x 8 groups of 16B) ---
  const int crow = lane >> 3;  // row within chunk
  const int grp = lane & 7;    // destination LDS 16B-group
  const unsigned short* gA[2];
  unsigned short* lA[2];
#pragma unroll
  for (int c = 0; c < 2; c++) {
    int r = wave * 16 + c * 8 + crow;
    gA[c] = A + (size_t)(m0 + r) * K + (size_t)((grp ^ (r & 7)) * 8);
    lA[c] = As + (wave * 16 + c * 8) * BK + lane * 8;
  }
  const int rB = wave * 8 + crow;
  const unsigned short* gB = B + (size_t)(n0 + rB) * K + (size_t)((grp ^ (rB & 7)) * 8);
  unsigned short* lB = Bs + (wave * 8) * BK + lane * 8;

  // --- fragment LDS pointers ---
  const int ra = wave * 16 + t16;
  const unsigned short* pa[2];
  const unsigned short* pb[2][2];
#pragma unroll
  for (int kk = 0; kk < 2; kk++)
    pa[kk] = As + ra * BK + ((kk * 4 + quad) ^ (ra & 7)) * 8;
#pragma unroll
  for (int ni = 0; ni < 2; ni++) {
    int rb = ni * 16 + t16;
#pragma unroll
    for (int kk = 0; kk < 2; kk++)
      pb[ni][kk] = Bs + rb * BK + ((kk * 4 + quad) ^ (rb & 7)) * 8;
  }

  f32x4 acc[2] = {{0.f, 0.f, 0.f, 0.f}, {0.f, 0.f, 0.f, 0.f}};

  for (int kt = 0; kt < K; kt += BK) {
    __syncthreads();
    load16_lds(gA[0] + kt, lA[0]);
    load16_lds(gA[1] + kt, lA[1]);
    load16_lds(gB + kt, lB);
    __syncthreads();
#pragma unroll
    for (int kk = 0; kk < 2; kk++) {
      bf16x8 a = *(const bf16x8*)pa[kk];
      bf16x8 b0v = *(const bf16x8*)pb[0][kk];
      bf16x8 b1v = *(const bf16x8*)pb[1][kk];
      acc[0] = __builtin_amdgcn_mfma_f32_16x16x32_bf16(a, b0v, acc[0], 0, 0, 0);
      acc[1] = __builtin_amdgcn_mfma_f32_16x16x32_bf16(a, b1v, acc[1], 0, 0, 0);
    }
  }

  // epilogue: C row = quad*4 + reg, col = t16 (m89-verified layout)
#pragma unroll
  for (int r = 0; r < 4; r++) {
    const int m = m0 + wave * 16 + quad * 4 + r;
#pragma unroll
    for (int ni = 0; ni < 2; ni++) {
      const int n = n0 + ni * 16 + t16;
      const size_t idx = (size_t)m * 1024 + n;
      if constexpr (MAIN) {
        outf[idx] = outf[idx] + acc[ni][r];  // coh partial already there
      } else {
        outb[idx] = f32_to_bf16_rne(acc[ni][r]);
      }
    }
  }
}

// ---------------------------------------------------------------------------
extern "C" void kernel_launch(void* const* d_in, const int* in_sizes, int n_in,
                              void* d_out, int out_size, void* d_ws, size_t ws_size,
                              hipStream_t stream) {
  const float* x   = (const float*)d_in[0];  // [2048,1024]
  const float* win = (const float*)d_in[1];  // [1024,1024]
  const float* wp  = (const float*)d_in[2];  // [8,1024,1024]
  const float* J   = (const float*)d_in[3];  // [8,8]
  const float* coh = (const float*)d_in[4];  // [2048,8,1024]
  const float* t   = (const float*)d_in[5];  // [1]
  float* out = (float*)d_out;                // [2048,1024] fp32

  char* ws = (char*)d_ws;
  unsigned short* xb    = (unsigned short*)ws;                       // 4 MB
  unsigned short* winb  = (unsigned short*)(ws + 4u * 1024 * 1024);  // 2 MB
  unsigned short* wefft = (unsigned short*)(ws + 6u * 1024 * 1024);  // 2 MB
  unsigned short* wct   = (unsigned short*)(ws + 8u * 1024 * 1024);  // 2 MB

  // converts + coh partial (into out) + Weff^T build
  k_prep<<<5376, 256, 0, stream>>>(x, win, wp, J, t, coh, xb, winb, wefft, out);
  // wct[h2][d] = sum_h1 wefft[h2][h1] * winb[d][h1]
  k_gemm<0><<<dim3(16, 32), 256, 0, stream>>>(wefft, winb, nullptr, wct);
  // out[b][h2] += sum_d xb[b][d] * wct[h2][d]
  k_gemm<1><<<dim3(32, 32), 256, 0, stream>>>(xb, wct, out, nullptr);
}